// Round 1
// baseline (1332.562 us; speedup 1.0000x reference)
//
#include <hip/hip_runtime.h>
#include <math.h>

#define T_TOK 8192
#define HDIM 1024
#define IDIM 512
#define NEXP 8
#define EPG 4     // experts per group
#define NGRP 2

#define BM 64
#define BN 64
#define BK 16

// ---------------- router: one wave per token ----------------
__global__ __launch_bounds__(256)
void router_kernel(const float* __restrict__ X,
                   const float* __restrict__ Wr,    // [E,H]
                   const float* __restrict__ bias,  // [E]
                   float* __restrict__ wpair,       // [2T]
                   int* __restrict__ counts,        // [E]
                   int* __restrict__ pair_id)       // [E*T]
{
    int wave = threadIdx.x >> 6;
    int lane = threadIdx.x & 63;
    int t = blockIdx.x * 4 + wave;
    if (t >= T_TOK) return;

    float acc[NEXP];
#pragma unroll
    for (int e = 0; e < NEXP; ++e) acc[e] = 0.f;

    const float4* X4 = (const float4*)(X + (size_t)t * HDIM);
#pragma unroll
    for (int jj = 0; jj < 4; ++jj) {
        float4 xv = X4[lane + jj * 64];
#pragma unroll
        for (int e = 0; e < NEXP; ++e) {
            const float4* W4 = (const float4*)(Wr + (size_t)e * HDIM);
            float4 wv = W4[lane + jj * 64];
            acc[e] += xv.x * wv.x + xv.y * wv.y + xv.z * wv.z + xv.w * wv.w;
        }
    }
#pragma unroll
    for (int e = 0; e < NEXP; ++e) {
#pragma unroll
        for (int off = 32; off >= 1; off >>= 1)
            acc[e] += __shfl_xor(acc[e], off, 64);
    }

    if (lane == 0) {
        float s[NEXP], b[NEXP];
#pragma unroll
        for (int e = 0; e < NEXP; ++e) {
            s[e] = 1.f / (1.f + expf(-acc[e]));
            b[e] = s[e] + bias[e];
        }
        // group score = sum of top-2 biased scores within each group of 4
        float gs[NGRP];
#pragma unroll
        for (int g = 0; g < NGRP; ++g) {
            float m1 = -1e30f, m2 = -1e30f;
#pragma unroll
            for (int j = 0; j < EPG; ++j) {
                float v = b[g * EPG + j];
                if (v > m1) { m2 = m1; m1 = v; }
                else if (v > m2) { m2 = v; }
            }
            gs[g] = m1 + m2;
        }
        int bg = (gs[1] > gs[0]) ? 1 : 0;   // jax top_k: first index wins ties
        float masked[NEXP];
#pragma unroll
        for (int e = 0; e < NEXP; ++e)
            masked[e] = ((e >> 2) == bg) ? b[e] : 0.0f;
        // top-1 (first occurrence on ties -> strict >)
        int i0 = 0; float v0 = masked[0];
#pragma unroll
        for (int e = 1; e < NEXP; ++e)
            if (masked[e] > v0) { v0 = masked[e]; i0 = e; }
        // top-2 excluding i0
        int i1 = -1; float v1 = -1e30f;
#pragma unroll
        for (int e = 0; e < NEXP; ++e) {
            if (e == i0) continue;
            if (masked[e] > v1) { v1 = masked[e]; i1 = e; }
        }
        float w0 = s[i0], w1 = s[i1];
        float inv = 1.f / (w0 + w1 + 1e-20f);
        w0 *= inv; w1 *= inv;   // routed_scaling_factor == 1.0
        wpair[t * 2 + 0] = w0;
        wpair[t * 2 + 1] = w1;
        int pos0 = atomicAdd(&counts[i0], 1);
        pair_id[i0 * T_TOK + pos0] = t * 2 + 0;
        int pos1 = atomicAdd(&counts[i1], 1);
        pair_id[i1 * T_TOK + pos1] = t * 2 + 1;
    }
}

// ---------------- fused gate/up GEMM + SiLU*up -> h ----------------
// C tile [BM x BN] of h[row, i] = silu(X@Wg)[row,i] * (X@Wu)[row,i]
template<bool GATHER>
__global__ __launch_bounds__(256)
void gateup_kernel(const float* __restrict__ X,     // [T,H]
                   const float* __restrict__ Wg,    // [H,I] (or [E,H,I])
                   const float* __restrict__ Wu,
                   float* __restrict__ hout,        // [rows, I]
                   const int* __restrict__ counts,
                   const int* __restrict__ pair_id)
{
    int e = blockIdx.z;
    int n = GATHER ? counts[e] : T_TOK;
    int bm0 = blockIdx.x * BM;
    if (bm0 >= n) return;
    int bn0 = blockIdx.y * BN;
    const float* wg = Wg + (GATHER ? (size_t)e * HDIM * IDIM : 0);
    const float* wu = Wu + (GATHER ? (size_t)e * HDIM * IDIM : 0);
    const int* plist = GATHER ? (pair_id + e * T_TOK) : nullptr;

    __shared__ float As[BK][BM + 4];
    __shared__ float Bg[BK][BN];
    __shared__ float Bu[BK][BN];

    int tid = threadIdx.x;
    int tx = tid & 15, ty = tid >> 4;

    // A-load assignment: one float4 per thread
    int ar = tid >> 2;            // 0..63  (tile-local row)
    int ac = (tid & 3) * 4;       // 0,4,8,12 (k within tile)
    int arow = bm0 + ar;
    bool avalid = arow < n;
    size_t asrc = 0;
    if (GATHER) {
        if (avalid) asrc = (size_t)(plist[arow] >> 1) * HDIM;
    } else {
        asrc = (size_t)arow * HDIM;
    }
    // B-load assignment
    int bkr = tid >> 4;           // 0..15
    int bc = (tid & 15) * 4;      // 0..60

    float cg[4][4] = {{0.f}};
    float cu[4][4] = {{0.f}};

    for (int k0 = 0; k0 < HDIM; k0 += BK) {
        float4 av = make_float4(0.f, 0.f, 0.f, 0.f);
        if (avalid) av = *(const float4*)(X + asrc + k0 + ac);
        As[ac + 0][ar] = av.x; As[ac + 1][ar] = av.y;
        As[ac + 2][ar] = av.z; As[ac + 3][ar] = av.w;
        *(float4*)&Bg[bkr][bc] = *(const float4*)(wg + (size_t)(k0 + bkr) * IDIM + bn0 + bc);
        *(float4*)&Bu[bkr][bc] = *(const float4*)(wu + (size_t)(k0 + bkr) * IDIM + bn0 + bc);
        __syncthreads();
#pragma unroll
        for (int k = 0; k < BK; ++k) {
            float4 a4 = *(const float4*)&As[k][ty * 4];
            float4 g4 = *(const float4*)&Bg[k][tx * 4];
            float4 u4 = *(const float4*)&Bu[k][tx * 4];
            float av_[4] = {a4.x, a4.y, a4.z, a4.w};
            float gv_[4] = {g4.x, g4.y, g4.z, g4.w};
            float uv_[4] = {u4.x, u4.y, u4.z, u4.w};
#pragma unroll
            for (int r = 0; r < 4; ++r)
#pragma unroll
                for (int c = 0; c < 4; ++c) {
                    cg[r][c] += av_[r] * gv_[c];
                    cu[r][c] += av_[r] * uv_[c];
                }
        }
        __syncthreads();
    }

#pragma unroll
    for (int r = 0; r < 4; ++r) {
        int row = ty * 4 + r;
        int grow = bm0 + row;
        if (grow >= n) continue;
        size_t dst;
        if (GATHER) dst = (size_t)plist[grow] * IDIM + bn0 + tx * 4;
        else        dst = (size_t)grow * IDIM + bn0 + tx * 4;
        float4 o;
        float* po = &o.x;
#pragma unroll
        for (int c = 0; c < 4; ++c) {
            float g = cg[r][c], u = cu[r][c];
            float sg = g / (1.f + expf(-g));
            po[c] = sg * u;
        }
        *(float4*)(hout + dst) = o;
    }
}

// ---------------- down GEMM: out[t] (+)= w * (h @ Wd) ----------------
template<bool GATHER>
__global__ __launch_bounds__(256)
void down_kernel(const float* __restrict__ Hbuf,   // [rows, I]
                 const float* __restrict__ Wd,     // [I,H] (or [E,I,H])
                 float* __restrict__ out,          // [T,H]
                 const int* __restrict__ counts,
                 const int* __restrict__ pair_id,
                 const float* __restrict__ wpair)
{
    int e = blockIdx.z;
    int n = GATHER ? counts[e] : T_TOK;
    int bm0 = blockIdx.x * BM;
    if (bm0 >= n) return;
    int bn0 = blockIdx.y * BN;
    const float* wd = Wd + (GATHER ? (size_t)e * IDIM * HDIM : 0);
    const int* plist = GATHER ? (pair_id + e * T_TOK) : nullptr;

    __shared__ float As[BK][BM + 4];
    __shared__ float Bs[BK][BN];

    int tid = threadIdx.x;
    int tx = tid & 15, ty = tid >> 4;
    int ar = tid >> 2;
    int ac = (tid & 3) * 4;
    int arow = bm0 + ar;
    bool avalid = arow < n;
    size_t asrc = 0;
    if (avalid) {
        int p = GATHER ? plist[arow] : arow;
        asrc = (size_t)p * IDIM;
    }
    int bkr = tid >> 4, bc = (tid & 15) * 4;

    float cc[4][4] = {{0.f}};

    for (int k0 = 0; k0 < IDIM; k0 += BK) {
        float4 av = make_float4(0.f, 0.f, 0.f, 0.f);
        if (avalid) av = *(const float4*)(Hbuf + asrc + k0 + ac);
        As[ac + 0][ar] = av.x; As[ac + 1][ar] = av.y;
        As[ac + 2][ar] = av.z; As[ac + 3][ar] = av.w;
        *(float4*)&Bs[bkr][bc] = *(const float4*)(wd + (size_t)(k0 + bkr) * HDIM + bn0 + bc);
        __syncthreads();
#pragma unroll
        for (int k = 0; k < BK; ++k) {
            float4 a4 = *(const float4*)&As[k][ty * 4];
            float4 b4 = *(const float4*)&Bs[k][tx * 4];
            float av_[4] = {a4.x, a4.y, a4.z, a4.w};
            float bv_[4] = {b4.x, b4.y, b4.z, b4.w};
#pragma unroll
            for (int r = 0; r < 4; ++r)
#pragma unroll
                for (int c = 0; c < 4; ++c)
                    cc[r][c] += av_[r] * bv_[c];
        }
        __syncthreads();
    }

#pragma unroll
    for (int r = 0; r < 4; ++r) {
        int row = ty * 4 + r;
        int grow = bm0 + row;
        if (grow >= n) continue;
        if (GATHER) {
            int p = plist[grow];
            int t = p >> 1;
            float w = wpair[p];
            float* dst = out + (size_t)t * HDIM + bn0 + tx * 4;
#pragma unroll
            for (int c = 0; c < 4; ++c)
                atomicAdd(dst + c, cc[r][c] * w);
        } else {
            float4 o = make_float4(cc[r][0], cc[r][1], cc[r][2], cc[r][3]);
            *(float4*)(out + (size_t)grow * HDIM + bn0 + tx * 4) = o;
        }
    }
}

extern "C" void kernel_launch(void* const* d_in, const int* in_sizes, int n_in,
                              void* d_out, int out_size, void* d_ws, size_t ws_size,
                              hipStream_t stream) {
    const float* X    = (const float*)d_in[0];   // [B,S,H] -> [T,H]
    const float* Wr   = (const float*)d_in[1];   // [E,H]
    const float* bias = (const float*)d_in[2];   // [E]
    const float* wg   = (const float*)d_in[3];   // [E,H,I]
    const float* wu   = (const float*)d_in[4];   // [E,H,I]
    const float* wdn  = (const float*)d_in[5];   // [E,I,H]
    const float* swg  = (const float*)d_in[6];   // [H,I]
    const float* swu  = (const float*)d_in[7];   // [H,I]
    const float* swd  = (const float*)d_in[8];   // [I,H]
    float* out = (float*)d_out;

    char* ws = (char*)d_ws;
    int*   counts  = (int*)ws;                                   // 32 B
    float* wpair   = (float*)(ws + 256);                         // 2T*4 = 64 KB
    int*   pair_id = (int*)(ws + 256 + 65536);                   // E*T*4 = 256 KB
    float* hs      = (float*)(ws + (1u << 20));                  // T*I*4 = 16 MB
    float* hp      = (float*)(ws + (1u << 20) + ((size_t)T_TOK * IDIM * 4)); // 2T*I*4 = 32 MB

    hipMemsetAsync(counts, 0, NEXP * sizeof(int), stream);
    router_kernel<<<T_TOK / 4, 256, 0, stream>>>(X, Wr, bias, wpair, counts, pair_id);

    // shared expert: h_s = silu(X@swg)*(X@swu)
    gateup_kernel<false><<<dim3(T_TOK / BM, IDIM / BN, 1), 256, 0, stream>>>(
        X, swg, swu, hs, nullptr, nullptr);
    // routed experts: h_p per (token,slot) pair
    gateup_kernel<true><<<dim3(T_TOK / BM, IDIM / BN, NEXP), 256, 0, stream>>>(
        X, wg, wu, hp, counts, pair_id);

    // shared down: out = h_s @ swd   (plain store, initializes out)
    down_kernel<false><<<dim3(T_TOK / BM, HDIM / BN, 1), 256, 0, stream>>>(
        hs, swd, out, nullptr, nullptr, nullptr);
    // routed down: out += w * (h_p @ Wd)   (atomicAdd scatter)
    down_kernel<true><<<dim3(T_TOK / BM, HDIM / BN, NEXP), 256, 0, stream>>>(
        hp, wdn, out, counts, pair_id, wpair);
}

// Round 2
// 445.610 us; speedup vs baseline: 2.9904x; 2.9904x over previous
//
#include <hip/hip_runtime.h>
#include <math.h>
#include <stdint.h>

#define T_TOK 8192
#define HDIM 1024
#define IDIM 512
#define NEXP 8
#define NGRP 2
#define EPG 4

typedef unsigned short u16;
typedef __attribute__((ext_vector_type(8))) short short8;   // 8 bf16 in 4 VGPRs
typedef __attribute__((ext_vector_type(4))) float f32x4;

// async global->LDS, 16B per lane; LDS dest must be wave-uniform base (HW adds lane*16)
#define GLD16(gp, lp) __builtin_amdgcn_global_load_lds(                        \
    (const __attribute__((address_space(1))) unsigned int*)(gp),               \
    (__attribute__((address_space(3))) unsigned int*)(lp), 16, 0, 0)

__device__ __forceinline__ u16 f2bf(float f) {  // RNE float->bf16
    unsigned int u = __float_as_uint(f);
    u += 0x7fffu + ((u >> 16) & 1u);
    return (u16)(u >> 16);
}

// ---------------- router: one wave per token; also emits bf16 X ----------------
__global__ __launch_bounds__(256)
void router_kernel(const float* __restrict__ X,
                   const float* __restrict__ Wr,    // [E,H]
                   const float* __restrict__ bias,  // [E]
                   u16* __restrict__ Xb,            // [T,H] bf16 out
                   float* __restrict__ wpair,       // [2T]
                   int* __restrict__ counts,        // [E]
                   int* __restrict__ pair_id)       // [E*T]
{
    int wave = threadIdx.x >> 6;
    int lane = threadIdx.x & 63;
    int t = blockIdx.x * 4 + wave;
    if (t >= T_TOK) return;

    float acc[NEXP];
#pragma unroll
    for (int e = 0; e < NEXP; ++e) acc[e] = 0.f;

    const float4* X4 = (const float4*)(X + (size_t)t * HDIM);
#pragma unroll
    for (int jj = 0; jj < 4; ++jj) {
        float4 xv = X4[lane + jj * 64];
        // bf16 conversion of X fused here
        ushort4 bv;
        bv.x = f2bf(xv.x); bv.y = f2bf(xv.y); bv.z = f2bf(xv.z); bv.w = f2bf(xv.w);
        *(ushort4*)(Xb + (size_t)t * HDIM + (size_t)(lane + jj * 64) * 4) = bv;
#pragma unroll
        for (int e = 0; e < NEXP; ++e) {
            const float4* W4 = (const float4*)(Wr + (size_t)e * HDIM);
            float4 wv = W4[lane + jj * 64];
            acc[e] += xv.x * wv.x + xv.y * wv.y + xv.z * wv.z + xv.w * wv.w;
        }
    }
#pragma unroll
    for (int e = 0; e < NEXP; ++e) {
#pragma unroll
        for (int off = 32; off >= 1; off >>= 1)
            acc[e] += __shfl_xor(acc[e], off, 64);
    }

    if (lane == 0) {
        float s[NEXP], b[NEXP];
#pragma unroll
        for (int e = 0; e < NEXP; ++e) {
            s[e] = 1.f / (1.f + expf(-acc[e]));
            b[e] = s[e] + bias[e];
        }
        float gs[NGRP];
#pragma unroll
        for (int g = 0; g < NGRP; ++g) {
            float m1 = -1e30f, m2 = -1e30f;
#pragma unroll
            for (int j = 0; j < EPG; ++j) {
                float v = b[g * EPG + j];
                if (v > m1) { m2 = m1; m1 = v; }
                else if (v > m2) { m2 = v; }
            }
            gs[g] = m1 + m2;
        }
        int bg = (gs[1] > gs[0]) ? 1 : 0;
        float masked[NEXP];
#pragma unroll
        for (int e = 0; e < NEXP; ++e)
            masked[e] = ((e >> 2) == bg) ? b[e] : 0.0f;
        int i0 = 0; float v0 = masked[0];
#pragma unroll
        for (int e = 1; e < NEXP; ++e)
            if (masked[e] > v0) { v0 = masked[e]; i0 = e; }
        int i1 = -1; float v1 = -1e30f;
#pragma unroll
        for (int e = 0; e < NEXP; ++e) {
            if (e == i0) continue;
            if (masked[e] > v1) { v1 = masked[e]; i1 = e; }
        }
        float w0 = s[i0], w1 = s[i1];
        float inv = 1.f / (w0 + w1 + 1e-20f);
        w0 *= inv; w1 *= inv;
        wpair[t * 2 + 0] = w0;
        wpair[t * 2 + 1] = w1;
        int pos0 = atomicAdd(&counts[i0], 1);
        pair_id[i0 * T_TOK + pos0] = t * 2 + 0;
        int pos1 = atomicAdd(&counts[i1], 1);
        pair_id[i1 * T_TOK + pos1] = t * 2 + 1;
    }
}

// ---------------- transpose + fp32->bf16 convert: in [b][R][C] -> out [b][C][R] ----------------
__global__ __launch_bounds__(256)
void transpose_convert(const float* __restrict__ in, u16* __restrict__ outp,
                       int R, int C)
{
    int b = blockIdx.z;
    const float* src = in + (size_t)b * R * C;
    u16* dst = outp + (size_t)b * R * C;
    int r0 = blockIdx.x * 64, c0 = blockIdx.y * 64;
    __shared__ float tile[64][65];
    int t = threadIdx.x;
    int row = t >> 2;
#pragma unroll
    for (int j = 0; j < 4; ++j) {
        int c = ((t & 3) + j * 4) * 4;
        *(float4*)&tile[row][c] = *(const float4*)(src + (size_t)(r0 + row) * C + c0 + c);
    }
    __syncthreads();
    int c = t >> 2;            // output row = input col
    int rchunk = (t & 3) * 16;
    __attribute__((aligned(16))) u16 pack[16];
#pragma unroll
    for (int i = 0; i < 16; ++i)
        pack[i] = f2bf(tile[rchunk + i][c]);
    uint4* d4 = (uint4*)(dst + (size_t)(c0 + c) * R + r0 + rchunk);
    d4[0] = *(uint4*)&pack[0];
    d4[1] = *(uint4*)&pack[8];
}

// ---------------- fused gate/up MFMA GEMM + SiLU -> h (bf16) ----------------
// A: Xb [T,H] (gathered rows for routed). B: WgT/WuT [(E,)I,H] = [N][K] row-major.
// Block tile: 128 rows x 64 cols (of both g,u). 4 waves, each 64x32. BK=64.
template<bool GATHER>
__global__ __launch_bounds__(256)
void gateup_mfma(const u16* __restrict__ Xb,
                 const u16* __restrict__ WgT,
                 const u16* __restrict__ WuT,
                 u16* __restrict__ hout,          // rows indexed by pair id (routed) or token (shared)
                 const int* __restrict__ counts,
                 const int* __restrict__ pair_id)
{
    const int e = blockIdx.z;
    const int nrows = GATHER ? counts[e] : T_TOK;
    const int bm0 = blockIdx.x * 128;
    if (bm0 >= nrows) return;
    const int bn0 = blockIdx.y * 64;
    const u16* wgT = WgT + (GATHER ? (size_t)e * HDIM * IDIM : 0);
    const u16* wuT = WuT + (GATHER ? (size_t)e * HDIM * IDIM : 0);
    const int* plist = GATHER ? (pair_id + e * T_TOK) : nullptr;

    __shared__ __attribute__((aligned(16))) short As[128 * 64];  // [row][8 slots of 8 bf16], XOR-swizzled
    __shared__ __attribute__((aligned(16))) short Bg[64 * 64];
    __shared__ __attribute__((aligned(16))) short Bu[64 * 64];

    const int tid = threadIdx.x;
    const int lane = tid & 63;
    const int wid = tid >> 6;

    // staging source pointers (pre-swizzled global source, linear LDS dest)
    const char* aptr[4];
#pragma unroll
    for (int i = 0; i < 4; ++i) {
        int r = (wid * 4 + i) * 8 + (lane >> 3);
        int row = bm0 + r;
        int srow;
        if (GATHER) srow = (row < nrows) ? (plist[row] >> 1) : 0;
        else        srow = row;                          // M exact multiple for shared
        int cslot = ((lane & 7) ^ (r & 7)) * 8;
        aptr[i] = (const char*)(Xb + (size_t)srow * HDIM + cslot);
    }
    const char* bgptr[2]; const char* buptr[2];
#pragma unroll
    for (int i = 0; i < 2; ++i) {
        int r = (wid * 2 + i) * 8 + (lane >> 3);
        int nn = bn0 + r;
        int cslot = ((lane & 7) ^ (r & 7)) * 8;
        bgptr[i] = (const char*)(wgT + (size_t)nn * HDIM + cslot);
        buptr[i] = (const char*)(wuT + (size_t)nn * HDIM + cslot);
    }

    const int wm = wid >> 1, wn = wid & 1;
    const int m0 = wm * 64, n0 = wn * 32;
    const int lr = lane & 15, lg = lane >> 4;

    f32x4 accg[4][2] = {};
    f32x4 accu[4][2] = {};

    for (int k0 = 0; k0 < HDIM; k0 += 64) {
#pragma unroll
        for (int i = 0; i < 4; ++i) {
            GLD16(aptr[i], (char*)As + (wid * 4 + i) * 1024);
            aptr[i] += 128;
        }
#pragma unroll
        for (int i = 0; i < 2; ++i) {
            GLD16(bgptr[i], (char*)Bg + (wid * 2 + i) * 1024);
            GLD16(buptr[i], (char*)Bu + (wid * 2 + i) * 1024);
            bgptr[i] += 128; buptr[i] += 128;
        }
        __syncthreads();   // drains vmcnt -> LDS tiles ready
#pragma unroll
        for (int kk = 0; kk < 2; ++kk) {
            short8 af[4], bgf[2], buf_[2];
#pragma unroll
            for (int mf = 0; mf < 4; ++mf) {
                int row = m0 + mf * 16 + lr;
                int slot = (kk * 4 + lg) ^ (row & 7);
                af[mf] = *(const short8*)((const char*)As + row * 128 + slot * 16);
            }
#pragma unroll
            for (int nf = 0; nf < 2; ++nf) {
                int row = n0 + nf * 16 + lr;
                int slot = (kk * 4 + lg) ^ (row & 7);
                bgf[nf]  = *(const short8*)((const char*)Bg + row * 128 + slot * 16);
                buf_[nf] = *(const short8*)((const char*)Bu + row * 128 + slot * 16);
            }
#pragma unroll
            for (int mf = 0; mf < 4; ++mf)
#pragma unroll
                for (int nf = 0; nf < 2; ++nf) {
                    accg[mf][nf] = __builtin_amdgcn_mfma_f32_16x16x32_bf16(af[mf], bgf[nf],  accg[mf][nf], 0, 0, 0);
                    accu[mf][nf] = __builtin_amdgcn_mfma_f32_16x16x32_bf16(af[mf], buf_[nf], accu[mf][nf], 0, 0, 0);
                }
        }
        __syncthreads();   // all reads done before next stage overwrites
    }

    // epilogue: C/D layout col=lane&15, row=4*(lane>>4)+reg
#pragma unroll
    for (int mf = 0; mf < 4; ++mf) {
#pragma unroll
        for (int j = 0; j < 4; ++j) {
            int row = bm0 + m0 + mf * 16 + lg * 4 + j;
            if (row >= nrows) continue;
            int outrow = GATHER ? plist[row] : row;
            u16* dst = hout + (size_t)outrow * IDIM + bn0 + n0 + lr;
#pragma unroll
            for (int nf = 0; nf < 2; ++nf) {
                float g = accg[mf][nf][j], u = accu[mf][nf][j];
                float sg = g / (1.f + __expf(-g));
                dst[nf * 16] = f2bf(sg * u);
            }
        }
    }
}

// ---------------- down MFMA GEMM: out (+)= (h @ Wd) ----------------
// A: h [rows, I] bf16. B: WdT [(E,)H,I] = [N][K] row-major. 128x128 tile, BK=64.
template<bool GATHER>
__global__ __launch_bounds__(256)
void down_mfma(const u16* __restrict__ Hb,
               const u16* __restrict__ WdT,
               float* __restrict__ out,           // [T,H]
               const int* __restrict__ counts,
               const int* __restrict__ pair_id,
               const float* __restrict__ wpair)
{
    const int e = blockIdx.z;
    const int nrows = GATHER ? counts[e] : T_TOK;
    const int bm0 = blockIdx.x * 128;
    if (bm0 >= nrows) return;
    const int bn0 = blockIdx.y * 128;
    const u16* wdT = WdT + (GATHER ? (size_t)e * HDIM * IDIM : 0);
    const int* plist = GATHER ? (pair_id + e * T_TOK) : nullptr;

    __shared__ __attribute__((aligned(16))) short As[128 * 64];
    __shared__ __attribute__((aligned(16))) short Bs[128 * 64];

    const int tid = threadIdx.x;
    const int lane = tid & 63;
    const int wid = tid >> 6;

    const char* aptr[4];
#pragma unroll
    for (int i = 0; i < 4; ++i) {
        int r = (wid * 4 + i) * 8 + (lane >> 3);
        int row = bm0 + r;
        int srow;
        if (GATHER) srow = (row < nrows) ? plist[row] : 0;   // pair index directly
        else        srow = row;
        int cslot = ((lane & 7) ^ (r & 7)) * 8;
        aptr[i] = (const char*)(Hb + (size_t)srow * IDIM + cslot);
    }
    const char* bptr[4];
#pragma unroll
    for (int i = 0; i < 4; ++i) {
        int r = (wid * 4 + i) * 8 + (lane >> 3);
        int nn = bn0 + r;
        int cslot = ((lane & 7) ^ (r & 7)) * 8;
        bptr[i] = (const char*)(wdT + (size_t)nn * IDIM + cslot);
    }

    const int wm = wid >> 1, wn = wid & 1;
    const int m0 = wm * 64, n0 = wn * 64;
    const int lr = lane & 15, lg = lane >> 4;

    f32x4 acc[4][4] = {};

    for (int k0 = 0; k0 < IDIM; k0 += 64) {
#pragma unroll
        for (int i = 0; i < 4; ++i) {
            GLD16(aptr[i], (char*)As + (wid * 4 + i) * 1024);
            GLD16(bptr[i], (char*)Bs + (wid * 4 + i) * 1024);
            aptr[i] += 128; bptr[i] += 128;
        }
        __syncthreads();
#pragma unroll
        for (int kk = 0; kk < 2; ++kk) {
            short8 af[4], bf[4];
#pragma unroll
            for (int mf = 0; mf < 4; ++mf) {
                int row = m0 + mf * 16 + lr;
                int slot = (kk * 4 + lg) ^ (row & 7);
                af[mf] = *(const short8*)((const char*)As + row * 128 + slot * 16);
            }
#pragma unroll
            for (int nf = 0; nf < 4; ++nf) {
                int row = n0 + nf * 16 + lr;
                int slot = (kk * 4 + lg) ^ (row & 7);
                bf[nf] = *(const short8*)((const char*)Bs + row * 128 + slot * 16);
            }
#pragma unroll
            for (int mf = 0; mf < 4; ++mf)
#pragma unroll
                for (int nf = 0; nf < 4; ++nf)
                    acc[mf][nf] = __builtin_amdgcn_mfma_f32_16x16x32_bf16(af[mf], bf[nf], acc[mf][nf], 0, 0, 0);
        }
        __syncthreads();
    }

#pragma unroll
    for (int mf = 0; mf < 4; ++mf) {
#pragma unroll
        for (int j = 0; j < 4; ++j) {
            int row = bm0 + m0 + mf * 16 + lg * 4 + j;
            if (row >= nrows) continue;
            if (GATHER) {
                int p = plist[row];
                int t = p >> 1;
                float w = wpair[p];
                float* dst = out + (size_t)t * HDIM + bn0 + n0 + lr;
#pragma unroll
                for (int nf = 0; nf < 4; ++nf)
                    atomicAdd(dst + nf * 16, acc[mf][nf][j] * w);
            } else {
                float* dst = out + (size_t)row * HDIM + bn0 + n0 + lr;
#pragma unroll
                for (int nf = 0; nf < 4; ++nf)
                    dst[nf * 16] = acc[mf][nf][j];
            }
        }
    }
}

extern "C" void kernel_launch(void* const* d_in, const int* in_sizes, int n_in,
                              void* d_out, int out_size, void* d_ws, size_t ws_size,
                              hipStream_t stream) {
    const float* X    = (const float*)d_in[0];
    const float* Wr   = (const float*)d_in[1];
    const float* bias = (const float*)d_in[2];
    const float* wg   = (const float*)d_in[3];
    const float* wu   = (const float*)d_in[4];
    const float* wdn  = (const float*)d_in[5];
    const float* swg  = (const float*)d_in[6];
    const float* swu  = (const float*)d_in[7];
    const float* swd  = (const float*)d_in[8];
    float* out = (float*)d_out;
    (void)in_sizes; (void)n_in; (void)out_size; (void)ws_size;

    char* ws = (char*)d_ws;
    const size_t MB = 1048576;
    int*   counts  = (int*)ws;                           // 32 B
    float* wpair   = (float*)(ws + 4096);                // 64 KB
    int*   pair_id = (int*)(ws + 4096 + 65536);          // 256 KB
    u16* Xb   = (u16*)(ws + 1 * MB);                     // 16 MB  [T,H]
    u16* wgT  = (u16*)(ws + 17 * MB);                    // 8 MB   [E,I,H]
    u16* wuT  = (u16*)(ws + 25 * MB);                    // 8 MB
    u16* wdnT = (u16*)(ws + 33 * MB);                    // 8 MB   [E,H,I]
    u16* swgT = (u16*)(ws + 41 * MB);                    // 1 MB   [I,H]
    u16* swuT = (u16*)(ws + 42 * MB);                    // 1 MB
    u16* swdT = (u16*)(ws + 43 * MB);                    // 1 MB   [H,I]
    u16* hbuf = (u16*)(ws + 44 * MB);                    // 16 MB: shared h in [0,8MB), routed h (by pair) full

    hipMemsetAsync(counts, 0, NEXP * sizeof(int), stream);
    router_kernel<<<T_TOK / 4, 256, 0, stream>>>(X, Wr, bias, Xb, wpair, counts, pair_id);

    transpose_convert<<<dim3(16, 8, NEXP), 256, 0, stream>>>(wg,  wgT,  HDIM, IDIM);
    transpose_convert<<<dim3(16, 8, NEXP), 256, 0, stream>>>(wu,  wuT,  HDIM, IDIM);
    transpose_convert<<<dim3(8, 16, NEXP), 256, 0, stream>>>(wdn, wdnT, IDIM, HDIM);
    transpose_convert<<<dim3(16, 8, 1),    256, 0, stream>>>(swg, swgT, HDIM, IDIM);
    transpose_convert<<<dim3(16, 8, 1),    256, 0, stream>>>(swu, swuT, HDIM, IDIM);
    transpose_convert<<<dim3(8, 16, 1),    256, 0, stream>>>(swd, swdT, IDIM, HDIM);

    // order matters: hs and hp share hbuf; shared pipeline must finish before routed gateup,
    // and shared down initializes `out` before routed down atomics accumulate.
    gateup_mfma<false><<<dim3(T_TOK / 128, IDIM / 64, 1), 256, 0, stream>>>(
        Xb, swgT, swuT, hbuf, nullptr, nullptr);
    down_mfma<false><<<dim3(T_TOK / 128, HDIM / 128, 1), 256, 0, stream>>>(
        hbuf, swdT, out, nullptr, nullptr, nullptr);
    gateup_mfma<true><<<dim3(T_TOK / 128, IDIM / 64, NEXP), 256, 0, stream>>>(
        Xb, wgT, wuT, hbuf, counts, pair_id);
    down_mfma<true><<<dim3(T_TOK / 128, HDIM / 128, NEXP), 256, 0, stream>>>(
        hbuf, wdnT, out, counts, pair_id, wpair);
}

// Round 3
// 275.220 us; speedup vs baseline: 4.8418x; 1.6191x over previous
//
#include <hip/hip_runtime.h>
#include <math.h>
#include <stdint.h>

#define T_TOK 8192
#define HDIM 1024
#define IDIM 512
#define NEXP 8
#define NGRP 2
#define EPG 4

typedef unsigned short u16;
typedef __attribute__((ext_vector_type(8))) short short8;   // 8 bf16 in 4 VGPRs
typedef __attribute__((ext_vector_type(4))) float f32x4;

// async global->LDS, 16B per lane; LDS dest must be wave-uniform base (HW adds lane*16)
#define GLD16(gp, lp) __builtin_amdgcn_global_load_lds(                        \
    (const __attribute__((address_space(1))) unsigned int*)(gp),               \
    (__attribute__((address_space(3))) unsigned int*)(lp), 16, 0, 0)

__device__ __forceinline__ u16 f2bf(float f) {  // RNE float->bf16
    unsigned int u = __float_as_uint(f);
    u += 0x7fffu + ((u >> 16) & 1u);
    return (u16)(u >> 16);
}

// ---------------- router: one wave per token; no atomics ----------------
__global__ __launch_bounds__(256)
void router_kernel(const float* __restrict__ X,
                   const float* __restrict__ Wr,    // [E,H]
                   const float* __restrict__ bias,  // [E]
                   u16* __restrict__ Xb,            // [T,H] bf16 out
                   float* __restrict__ wpair,       // [2T]
                   int* __restrict__ topk_ids)      // [T] packed i0 | i1<<8
{
    int wave = threadIdx.x >> 6;
    int lane = threadIdx.x & 63;
    int t = blockIdx.x * 4 + wave;
    if (t >= T_TOK) return;

    float acc[NEXP];
#pragma unroll
    for (int e = 0; e < NEXP; ++e) acc[e] = 0.f;

    const float4* X4 = (const float4*)(X + (size_t)t * HDIM);
#pragma unroll
    for (int jj = 0; jj < 4; ++jj) {
        float4 xv = X4[lane + jj * 64];
        ushort4 bv;
        bv.x = f2bf(xv.x); bv.y = f2bf(xv.y); bv.z = f2bf(xv.z); bv.w = f2bf(xv.w);
        *(ushort4*)(Xb + (size_t)t * HDIM + (size_t)(lane + jj * 64) * 4) = bv;
#pragma unroll
        for (int e = 0; e < NEXP; ++e) {
            const float4* W4 = (const float4*)(Wr + (size_t)e * HDIM);
            float4 wv = W4[lane + jj * 64];
            acc[e] += xv.x * wv.x + xv.y * wv.y + xv.z * wv.z + xv.w * wv.w;
        }
    }
#pragma unroll
    for (int e = 0; e < NEXP; ++e) {
#pragma unroll
        for (int off = 32; off >= 1; off >>= 1)
            acc[e] += __shfl_xor(acc[e], off, 64);
    }

    if (lane == 0) {
        float s[NEXP], b[NEXP];
#pragma unroll
        for (int e = 0; e < NEXP; ++e) {
            s[e] = 1.f / (1.f + expf(-acc[e]));
            b[e] = s[e] + bias[e];
        }
        float gs[NGRP];
#pragma unroll
        for (int g = 0; g < NGRP; ++g) {
            float m1 = -1e30f, m2 = -1e30f;
#pragma unroll
            for (int j = 0; j < EPG; ++j) {
                float v = b[g * EPG + j];
                if (v > m1) { m2 = m1; m1 = v; }
                else if (v > m2) { m2 = v; }
            }
            gs[g] = m1 + m2;
        }
        int bg = (gs[1] > gs[0]) ? 1 : 0;
        float masked[NEXP];
#pragma unroll
        for (int e = 0; e < NEXP; ++e)
            masked[e] = ((e >> 2) == bg) ? b[e] : 0.0f;
        int i0 = 0; float v0 = masked[0];
#pragma unroll
        for (int e = 1; e < NEXP; ++e)
            if (masked[e] > v0) { v0 = masked[e]; i0 = e; }
        int i1 = -1; float v1 = -1e30f;
#pragma unroll
        for (int e = 0; e < NEXP; ++e) {
            if (e == i0) continue;
            if (masked[e] > v1) { v1 = masked[e]; i1 = e; }
        }
        float w0 = s[i0], w1 = s[i1];
        float inv = 1.f / (w0 + w1 + 1e-20f);
        w0 *= inv; w1 *= inv;
        wpair[t * 2 + 0] = w0;
        wpair[t * 2 + 1] = w1;
        topk_ids[t] = i0 | (i1 << 8);
    }
}

// ---------------- build per-expert pair lists (deterministic compaction) ----------------
// one block per expert; ballot + popcount stream compaction over all tokens
__global__ __launch_bounds__(256)
void build_lists(const int* __restrict__ topk_ids,
                 int* __restrict__ counts,
                 int* __restrict__ pair_id)
{
    const int e = blockIdx.x;
    const int tid = threadIdx.x;
    const int lane = tid & 63;
    const int wid = tid >> 6;
    __shared__ int wsum[4];
    __shared__ int rb;
    if (tid == 0) rb = 0;
    __syncthreads();

    int* dst = pair_id + e * T_TOK;
    for (int c0 = 0; c0 < T_TOK; c0 += 256) {
        int t = c0 + tid;
        int ids = topk_ids[t];
        bool m0 = (ids & 0xff) == e;
        bool m1 = ((ids >> 8) & 0xff) == e;
        unsigned long long b0 = __ballot(m0);
        unsigned long long b1 = __ballot(m1);
        int n0 = __popcll(b0);
        int n1 = __popcll(b1);
        if (lane == 0) wsum[wid] = n0 + n1;
        __syncthreads();
        int pre = 0, tot = 0;
#pragma unroll
        for (int w = 0; w < 4; ++w) {
            int v = wsum[w];
            if (w < wid) pre += v;
            tot += v;
        }
        int mybase = rb + pre;
        unsigned long long ltmask = (lane == 63) ? ~0ull >> 1 : ((1ull << lane) - 1);
        if (m0) dst[mybase + __popcll(b0 & ltmask)] = t * 2;
        if (m1) dst[mybase + n0 + __popcll(b1 & ltmask)] = t * 2 + 1;
        __syncthreads();
        if (tid == 0) rb += tot;
        // next iteration's first __syncthreads orders this update before reads
    }
    __syncthreads();
    if (tid == 0) counts[e] = rb;
}

// ---------------- transpose + fp32->bf16 convert: in [b][R][C] -> out [b][C][R] ----------------
__global__ __launch_bounds__(256)
void transpose_convert(const float* __restrict__ in, u16* __restrict__ outp,
                       int R, int C)
{
    int b = blockIdx.z;
    const float* src = in + (size_t)b * R * C;
    u16* dst = outp + (size_t)b * R * C;
    int r0 = blockIdx.x * 64, c0 = blockIdx.y * 64;
    __shared__ float tile[64][65];
    int t = threadIdx.x;
    int row = t >> 2;
#pragma unroll
    for (int j = 0; j < 4; ++j) {
        int c = ((t & 3) + j * 4) * 4;
        *(float4*)&tile[row][c] = *(const float4*)(src + (size_t)(r0 + row) * C + c0 + c);
    }
    __syncthreads();
    int c = t >> 2;            // output row = input col
    int rchunk = (t & 3) * 16;
    __attribute__((aligned(16))) u16 pack[16];
#pragma unroll
    for (int i = 0; i < 16; ++i)
        pack[i] = f2bf(tile[rchunk + i][c]);
    uint4* d4 = (uint4*)(dst + (size_t)(c0 + c) * R + r0 + rchunk);
    d4[0] = *(uint4*)&pack[0];
    d4[1] = *(uint4*)&pack[8];
}

// ---------------- fused gate/up MFMA GEMM + SiLU -> h (bf16) ----------------
template<bool GATHER>
__global__ __launch_bounds__(256)
void gateup_mfma(const u16* __restrict__ Xb,
                 const u16* __restrict__ WgT,
                 const u16* __restrict__ WuT,
                 u16* __restrict__ hout,
                 const int* __restrict__ counts,
                 const int* __restrict__ pair_id)
{
    const int e = blockIdx.z;
    const int nrows = GATHER ? counts[e] : T_TOK;
    const int bm0 = blockIdx.x * 128;
    if (bm0 >= nrows) return;
    const int bn0 = blockIdx.y * 64;
    const u16* wgT = WgT + (GATHER ? (size_t)e * HDIM * IDIM : 0);
    const u16* wuT = WuT + (GATHER ? (size_t)e * HDIM * IDIM : 0);
    const int* plist = GATHER ? (pair_id + e * T_TOK) : nullptr;

    __shared__ __attribute__((aligned(16))) short As[128 * 64];
    __shared__ __attribute__((aligned(16))) short Bg[64 * 64];
    __shared__ __attribute__((aligned(16))) short Bu[64 * 64];

    const int tid = threadIdx.x;
    const int lane = tid & 63;
    const int wid = tid >> 6;

    const char* aptr[4];
#pragma unroll
    for (int i = 0; i < 4; ++i) {
        int r = (wid * 4 + i) * 8 + (lane >> 3);
        int row = bm0 + r;
        int srow;
        if (GATHER) srow = (row < nrows) ? (plist[row] >> 1) : 0;
        else        srow = row;
        int cslot = ((lane & 7) ^ (r & 7)) * 8;
        aptr[i] = (const char*)(Xb + (size_t)srow * HDIM + cslot);
    }
    const char* bgptr[2]; const char* buptr[2];
#pragma unroll
    for (int i = 0; i < 2; ++i) {
        int r = (wid * 2 + i) * 8 + (lane >> 3);
        int nn = bn0 + r;
        int cslot = ((lane & 7) ^ (r & 7)) * 8;
        bgptr[i] = (const char*)(wgT + (size_t)nn * HDIM + cslot);
        buptr[i] = (const char*)(wuT + (size_t)nn * HDIM + cslot);
    }

    const int wm = wid >> 1, wn = wid & 1;
    const int m0 = wm * 64, n0 = wn * 32;
    const int lr = lane & 15, lg = lane >> 4;

    f32x4 accg[4][2] = {};
    f32x4 accu[4][2] = {};

    for (int k0 = 0; k0 < HDIM; k0 += 64) {
#pragma unroll
        for (int i = 0; i < 4; ++i) {
            GLD16(aptr[i], (char*)As + (wid * 4 + i) * 1024);
            aptr[i] += 128;
        }
#pragma unroll
        for (int i = 0; i < 2; ++i) {
            GLD16(bgptr[i], (char*)Bg + (wid * 2 + i) * 1024);
            GLD16(buptr[i], (char*)Bu + (wid * 2 + i) * 1024);
            bgptr[i] += 128; buptr[i] += 128;
        }
        __syncthreads();
#pragma unroll
        for (int kk = 0; kk < 2; ++kk) {
            short8 af[4], bgf[2], buf_[2];
#pragma unroll
            for (int mf = 0; mf < 4; ++mf) {
                int row = m0 + mf * 16 + lr;
                int slot = (kk * 4 + lg) ^ (row & 7);
                af[mf] = *(const short8*)((const char*)As + row * 128 + slot * 16);
            }
#pragma unroll
            for (int nf = 0; nf < 2; ++nf) {
                int row = n0 + nf * 16 + lr;
                int slot = (kk * 4 + lg) ^ (row & 7);
                bgf[nf]  = *(const short8*)((const char*)Bg + row * 128 + slot * 16);
                buf_[nf] = *(const short8*)((const char*)Bu + row * 128 + slot * 16);
            }
#pragma unroll
            for (int mf = 0; mf < 4; ++mf)
#pragma unroll
                for (int nf = 0; nf < 2; ++nf) {
                    accg[mf][nf] = __builtin_amdgcn_mfma_f32_16x16x32_bf16(af[mf], bgf[nf],  accg[mf][nf], 0, 0, 0);
                    accu[mf][nf] = __builtin_amdgcn_mfma_f32_16x16x32_bf16(af[mf], buf_[nf], accu[mf][nf], 0, 0, 0);
                }
        }
        __syncthreads();
    }

#pragma unroll
    for (int mf = 0; mf < 4; ++mf) {
#pragma unroll
        for (int j = 0; j < 4; ++j) {
            int row = bm0 + m0 + mf * 16 + lg * 4 + j;
            if (row >= nrows) continue;
            int outrow = GATHER ? plist[row] : row;
            u16* dst = hout + (size_t)outrow * IDIM + bn0 + n0 + lr;
#pragma unroll
            for (int nf = 0; nf < 2; ++nf) {
                float g = accg[mf][nf][j], u = accu[mf][nf][j];
                float sg = g / (1.f + __expf(-g));
                dst[nf * 16] = f2bf(sg * u);
            }
        }
    }
}

// ---------------- down MFMA GEMM: out (+)= (h @ Wd) ----------------
template<bool GATHER>
__global__ __launch_bounds__(256)
void down_mfma(const u16* __restrict__ Hb,
               const u16* __restrict__ WdT,
               float* __restrict__ out,
               const int* __restrict__ counts,
               const int* __restrict__ pair_id,
               const float* __restrict__ wpair)
{
    const int e = blockIdx.z;
    const int nrows = GATHER ? counts[e] : T_TOK;
    const int bm0 = blockIdx.x * 128;
    if (bm0 >= nrows) return;
    const int bn0 = blockIdx.y * 128;
    const u16* wdT = WdT + (GATHER ? (size_t)e * HDIM * IDIM : 0);
    const int* plist = GATHER ? (pair_id + e * T_TOK) : nullptr;

    __shared__ __attribute__((aligned(16))) short As[128 * 64];
    __shared__ __attribute__((aligned(16))) short Bs[128 * 64];

    const int tid = threadIdx.x;
    const int lane = tid & 63;
    const int wid = tid >> 6;

    const char* aptr[4];
#pragma unroll
    for (int i = 0; i < 4; ++i) {
        int r = (wid * 4 + i) * 8 + (lane >> 3);
        int row = bm0 + r;
        int srow;
        if (GATHER) srow = (row < nrows) ? plist[row] : 0;
        else        srow = row;
        int cslot = ((lane & 7) ^ (r & 7)) * 8;
        aptr[i] = (const char*)(Hb + (size_t)srow * IDIM + cslot);
    }
    const char* bptr[4];
#pragma unroll
    for (int i = 0; i < 4; ++i) {
        int r = (wid * 4 + i) * 8 + (lane >> 3);
        int nn = bn0 + r;
        int cslot = ((lane & 7) ^ (r & 7)) * 8;
        bptr[i] = (const char*)(wdT + (size_t)nn * IDIM + cslot);
    }

    const int wm = wid >> 1, wn = wid & 1;
    const int m0 = wm * 64, n0 = wn * 64;
    const int lr = lane & 15, lg = lane >> 4;

    f32x4 acc[4][4] = {};

    for (int k0 = 0; k0 < IDIM; k0 += 64) {
#pragma unroll
        for (int i = 0; i < 4; ++i) {
            GLD16(aptr[i], (char*)As + (wid * 4 + i) * 1024);
            GLD16(bptr[i], (char*)Bs + (wid * 4 + i) * 1024);
            aptr[i] += 128; bptr[i] += 128;
        }
        __syncthreads();
#pragma unroll
        for (int kk = 0; kk < 2; ++kk) {
            short8 af[4], bf[4];
#pragma unroll
            for (int mf = 0; mf < 4; ++mf) {
                int row = m0 + mf * 16 + lr;
                int slot = (kk * 4 + lg) ^ (row & 7);
                af[mf] = *(const short8*)((const char*)As + row * 128 + slot * 16);
            }
#pragma unroll
            for (int nf = 0; nf < 4; ++nf) {
                int row = n0 + nf * 16 + lr;
                int slot = (kk * 4 + lg) ^ (row & 7);
                bf[nf] = *(const short8*)((const char*)Bs + row * 128 + slot * 16);
            }
#pragma unroll
            for (int mf = 0; mf < 4; ++mf)
#pragma unroll
                for (int nf = 0; nf < 4; ++nf)
                    acc[mf][nf] = __builtin_amdgcn_mfma_f32_16x16x32_bf16(af[mf], bf[nf], acc[mf][nf], 0, 0, 0);
        }
        __syncthreads();
    }

#pragma unroll
    for (int mf = 0; mf < 4; ++mf) {
#pragma unroll
        for (int j = 0; j < 4; ++j) {
            int row = bm0 + m0 + mf * 16 + lg * 4 + j;
            if (row >= nrows) continue;
            if (GATHER) {
                int p = plist[row];
                int t = p >> 1;
                float w = wpair[p];
                float* dst = out + (size_t)t * HDIM + bn0 + n0 + lr;
#pragma unroll
                for (int nf = 0; nf < 4; ++nf)
                    atomicAdd(dst + nf * 16, acc[mf][nf][j] * w);
            } else {
                float* dst = out + (size_t)row * HDIM + bn0 + n0 + lr;
#pragma unroll
                for (int nf = 0; nf < 4; ++nf)
                    dst[nf * 16] = acc[mf][nf][j];
            }
        }
    }
}

extern "C" void kernel_launch(void* const* d_in, const int* in_sizes, int n_in,
                              void* d_out, int out_size, void* d_ws, size_t ws_size,
                              hipStream_t stream) {
    const float* X    = (const float*)d_in[0];
    const float* Wr   = (const float*)d_in[1];
    const float* bias = (const float*)d_in[2];
    const float* wg   = (const float*)d_in[3];
    const float* wu   = (const float*)d_in[4];
    const float* wdn  = (const float*)d_in[5];
    const float* swg  = (const float*)d_in[6];
    const float* swu  = (const float*)d_in[7];
    const float* swd  = (const float*)d_in[8];
    float* out = (float*)d_out;
    (void)in_sizes; (void)n_in; (void)out_size; (void)ws_size;

    char* ws = (char*)d_ws;
    const size_t MB = 1048576;
    int*   counts   = (int*)ws;                          // 32 B
    float* wpair    = (float*)(ws + 4096);               // 64 KB
    int*   pair_id  = (int*)(ws + 4096 + 65536);         // 256 KB
    int*   topk_ids = (int*)(ws + 524288);               // 32 KB
    u16* Xb   = (u16*)(ws + 1 * MB);                     // 16 MB  [T,H]
    u16* wgT  = (u16*)(ws + 17 * MB);                    // 8 MB   [E,I,H]
    u16* wuT  = (u16*)(ws + 25 * MB);                    // 8 MB
    u16* wdnT = (u16*)(ws + 33 * MB);                    // 8 MB   [E,H,I]
    u16* swgT = (u16*)(ws + 41 * MB);                    // 1 MB   [I,H]
    u16* swuT = (u16*)(ws + 42 * MB);                    // 1 MB
    u16* swdT = (u16*)(ws + 43 * MB);                    // 1 MB   [H,I]
    u16* hbuf = (u16*)(ws + 44 * MB);                    // 16 MB shared/routed (sequenced)

    router_kernel<<<T_TOK / 4, 256, 0, stream>>>(X, Wr, bias, Xb, wpair, topk_ids);
    build_lists<<<NEXP, 256, 0, stream>>>(topk_ids, counts, pair_id);

    transpose_convert<<<dim3(16, 8, NEXP), 256, 0, stream>>>(wg,  wgT,  HDIM, IDIM);
    transpose_convert<<<dim3(16, 8, NEXP), 256, 0, stream>>>(wu,  wuT,  HDIM, IDIM);
    transpose_convert<<<dim3(8, 16, NEXP), 256, 0, stream>>>(wdn, wdnT, IDIM, HDIM);
    transpose_convert<<<dim3(16, 8, 1),    256, 0, stream>>>(swg, swgT, HDIM, IDIM);
    transpose_convert<<<dim3(16, 8, 1),    256, 0, stream>>>(swu, swuT, HDIM, IDIM);
    transpose_convert<<<dim3(8, 16, 1),    256, 0, stream>>>(swd, swdT, IDIM, HDIM);

    // order matters: hs and hp share hbuf; shared pipeline must finish before routed gateup,
    // and shared down initializes `out` before routed down atomics accumulate.
    gateup_mfma<false><<<dim3(T_TOK / 128, IDIM / 64, 1), 256, 0, stream>>>(
        Xb, swgT, swuT, hbuf, nullptr, nullptr);
    down_mfma<false><<<dim3(T_TOK / 128, HDIM / 128, 1), 256, 0, stream>>>(
        hbuf, swdT, out, nullptr, nullptr, nullptr);
    gateup_mfma<true><<<dim3(T_TOK / 128, IDIM / 64, NEXP), 256, 0, stream>>>(
        Xb, wgT, wuT, hbuf, counts, pair_id);
    down_mfma<true><<<dim3(T_TOK / 128, HDIM / 128, NEXP), 256, 0, stream>>>(
        hbuf, wdnT, out, counts, pair_id, wpair);
}